// Round 2
// baseline (813.183 us; speedup 1.0000x reference)
//
#include <hip/hip_runtime.h>
#include <hip/hip_bf16.h>

typedef __attribute__((ext_vector_type(8))) __bf16 bf16x8;
typedef __attribute__((ext_vector_type(4))) __bf16 bf16x4;
typedef __attribute__((ext_vector_type(16))) float f32x16;

#define D_IN   2048
#define D_FF   8192
#define D_OUT  2048
#define BATCH  4096
#define SIZE_N 5794
#define SIZE_M 2897
// padded GEMM1 dims
#define PN 5888   // 46*128
#define PK 2944   // 92*32

#define OFF_B1 16777216
#define OFF_W2 16785408
#define OFF_B2 33562624

#define BK   32
#define NBUF 3

__device__ __forceinline__ void gload_lds16(const __bf16* g, __bf16* lds) {
    __builtin_amdgcn_global_load_lds(
        (const __attribute__((address_space(1))) void*)g,
        (__attribute__((address_space(3))) void*)lds,
        16, 0, 0);
}

template<int N> __device__ __forceinline__ void wait_vmcnt() {
    static_assert(N == 0 || N == 3 || N == 4 || N == 6 || N == 8, "unsupported vmcnt");
    if constexpr (N == 0)      asm volatile("s_waitcnt vmcnt(0)" ::: "memory");
    else if constexpr (N == 3) asm volatile("s_waitcnt vmcnt(3)" ::: "memory");
    else if constexpr (N == 4) asm volatile("s_waitcnt vmcnt(4)" ::: "memory");
    else if constexpr (N == 6) asm volatile("s_waitcnt vmcnt(6)" ::: "memory");
    else                       asm volatile("s_waitcnt vmcnt(8)" ::: "memory");
}
__device__ __forceinline__ void wait_lgkm0() {
    asm volatile("s_waitcnt lgkmcnt(0)" ::: "memory");
}

// C = A (M x K, row-major) * B^T (B is N x K, row-major), bf16 in, fp32 acc.
// m201-style fine-phase schedule, kstep-phases:
//   phase = one K-step of 16 (2 phases per BK=32 K-tile). Per phase:
//     {FM+FN ds_read_b128; stage 1 unit of tile t+2; sched_barrier; s_barrier;
//      lgkmcnt(0); sched_barrier; setprio(1); FM*FN MFMA; setprio(0);
//      [phase 2 only: counted vmcnt]; s_barrier}
//   NBUF=3 rotating buffers; stage targets tile t+2 (A at phase1, B at phase2).
//   Safety: buf[(t+2)%3] was last read by tile t-1; those ds_reads retired at
//   its lgkmcnt(0) before its end-barrier, which precedes this stage issue.
//   Wait: end of t.p2 vmcnt(G) leaves only tile t+2's G loads outstanding ->
//   tile t+1 guaranteed landed; barrier makes it collective. Never drains
//   except the single tile nt-2 (vmcnt 0 there, negligible).
// LDS row = 32 bf16 = 4 chunks of 16B; chunk c of row r at slot c ^ ((r>>1)&3)
// (conflict-free by construction for the fragment reads; staging keeps the LDS
// dest linear as global_load_lds requires and pre-swizzles the GLOBAL chunk:
// (tid&3) ^ ((tid>>3)&3), since (row*4+sl)>>3 == row>>1 exactly).
// MODE 0: store bf16, bounds-checked, no bias
// MODE 1: +bias, relu, store bf16
// MODE 2: +bias, store fp32
template<int MODE, int BM, int BN, int WM, int WN, int THREADS, int WEU>
__global__ __launch_bounds__(THREADS, WEU)
void gemm_p(const __bf16* __restrict__ A, int lda,
            const __bf16* __restrict__ B, int ldb,
            void* __restrict__ Cv, int ldc,
            const __bf16* __restrict__ bias,
            int K, int Mvalid, int Nvalid)
{
    constexpr int GA = (BM * 4) / THREADS;   // A gloads per thread per K-tile
    constexpr int GB = (BN * 4) / THREADS;
    constexpr int G  = GA + GB;
    constexpr int FM = BM / (WM * 32);       // 32-row frags per wave
    constexpr int FN = BN / (WN * 32);
    constexpr int TILE = (BM + BN) * 4;      // bf16x8 units per K-tile buffer

    __shared__ bf16x8 lds[NBUF * TILE];

    const int tid  = threadIdx.x;
    const int wave = tid >> 6;
    const int lane = tid & 63;
    const int wm   = wave / WN;
    const int wn   = wave % WN;

    const int bm0 = blockIdx.x * BM;
    const int bn0 = blockIdx.y * BN;

    // staging: thread covers LDS unit (g*THREADS + tid): row = idx>>2, slot = idx&3;
    // fetch global chunk (idx&3)^((idx>>3)&3) so slot sl of row r holds chunk
    // sl ^ ((r>>1)&3). g*THREADS doesn't perturb either term (THREADS mult of 32).
    const int srow   = tid >> 2;
    const int schunk = ((tid & 3) ^ ((tid >> 3) & 3)) * 8;
    const __bf16* aS = A + (size_t)(bm0 + srow) * lda + schunk;
    const __bf16* bS = B + (size_t)(bn0 + srow) * ldb + schunk;

    auto stageA = [&](bf16x8* buf, int t) {
        const size_t kof = (size_t)t * BK;
        #pragma unroll
        for (int g = 0; g < GA; ++g)
            gload_lds16(aS + kof + (size_t)(g * (THREADS / 4)) * lda,
                        (__bf16*)&buf[g * THREADS + tid]);
    };
    auto stageB = [&](bf16x8* buf, int t) {
        const size_t kof = (size_t)t * BK;
        #pragma unroll
        for (int g = 0; g < GB; ++g)
            gload_lds16(bS + kof + (size_t)(g * (THREADS / 4)) * ldb,
                        (__bf16*)&buf[BM * 4 + g * THREADS + tid]);
    };

    // fragment read coords: chunk c = 2*ks + kh at slot c ^ ((fr>>1)&3)
    const int fr  = lane & 31;
    const int kh  = lane >> 5;
    const int sl0 = kh ^ ((fr >> 1) & 3);

    int aOff[FM], bOff[FN];
    #pragma unroll
    for (int m = 0; m < FM; ++m) aOff[m] = (wm * (BM / WM) + m * 32 + fr) * 4;
    #pragma unroll
    for (int n = 0; n < FN; ++n) bOff[n] = (wn * (BN / WN) + n * 32 + fr) * 4;

    f32x16 acc[FM][FN] = {};

    const int nt = K / BK;   // >= 64 for all callers

    stageA(lds, 0);        stageB(lds, 0);
    stageA(lds + TILE, 1); stageB(lds + TILE, 1);
    wait_vmcnt<G>();                    // tile 0 landed (tile 1 in flight)
    __builtin_amdgcn_s_barrier();

    int cur = 0, stg = 2;
    for (int t = 0; t < nt; ++t) {
        bf16x8* bufA = lds + cur * TILE;
        bf16x8* sbuf = lds + stg * TILE;
        #pragma unroll
        for (int ks = 0; ks < 2; ++ks) {
            const int sl = sl0 ^ (ks << 1);
            bf16x8 af[FM], bq[FN];
            #pragma unroll
            for (int m = 0; m < FM; ++m) af[m] = bufA[aOff[m] + sl];
            #pragma unroll
            for (int n = 0; n < FN; ++n) bq[n] = bufA[BM * 4 + bOff[n] + sl];
            if (t + 2 < nt) {
                if (ks == 0) stageA(sbuf, t + 2);
                else         stageB(sbuf, t + 2);
            }
            __builtin_amdgcn_sched_barrier(0);
            __builtin_amdgcn_s_barrier();            // phase barrier #1
            wait_lgkm0();
            __builtin_amdgcn_sched_barrier(0);       // rule 18: pin MFMA after wait
            __builtin_amdgcn_s_setprio(1);
            #pragma unroll
            for (int m = 0; m < FM; ++m) {
                #pragma unroll
                for (int n = 0; n < FN; ++n)
                    acc[m][n] = __builtin_amdgcn_mfma_f32_32x32x16_bf16(
                        af[m], bq[n], acc[m][n], 0, 0, 0);
            }
            __builtin_amdgcn_s_setprio(0);
            if (ks == 1 && t < nt - 1) {
                if (t + 2 < nt) wait_vmcnt<G>();     // tile t+1 landed; t+2 in flight
                else            wait_vmcnt<0>();     // only at t = nt-2
            }
            __builtin_amdgcn_sched_barrier(0);
            if (!(ks == 1 && t == nt - 1))
                __builtin_amdgcn_s_barrier();        // phase barrier #2
        }
        cur = (cur == NBUF - 1) ? 0 : cur + 1;
        stg = (stg == NBUF - 1) ? 0 : stg + 1;
    }

    // epilogue: C/D layout col=lane&31, row=(reg&3)+8*(reg>>2)+4*(lane>>5)
    const int ecol = lane & 31;
    const int er0  = 4 * kh;
    #pragma unroll
    for (int m = 0; m < FM; ++m) {
        #pragma unroll
        for (int n = 0; n < FN; ++n) {
            const int colBase = bn0 + wn * (BN / WN) + n * 32 + ecol;
            #pragma unroll
            for (int reg = 0; reg < 16; ++reg) {
                const int row = bm0 + wm * (BM / WM) + m * 32
                              + (reg & 3) + 8 * (reg >> 2) + er0;
                float v = acc[m][n][reg];
                if constexpr (MODE == 0) {
                    if (row < Mvalid && colBase < Nvalid)
                        ((__bf16*)Cv)[(size_t)row * ldc + colBase] = (__bf16)v;
                } else if constexpr (MODE == 1) {
                    v += (float)bias[colBase];
                    v = v > 0.f ? v : 0.f;
                    ((__bf16*)Cv)[(size_t)row * ldc + colBase] = (__bf16)v;
                } else {
                    v += (float)bias[colBase];
                    ((float*)Cv)[(size_t)row * ldc + colBase] = v;
                }
            }
        }
    }
}

// fp32 (rows x cols) -> zero-padded bf16 (prows x pcols), row-major
__global__ void pad_cvt_bf16(const float* __restrict__ in, __bf16* __restrict__ out,
                             int rows, int cols, int pcols, int total)
{
    int idx = blockIdx.x * blockDim.x + threadIdx.x;
    if (idx >= total) return;
    int r = idx / pcols;
    int c = idx - r * pcols;
    float v = (r < rows && c < cols) ? in[(size_t)r * cols + c] : 0.0f;
    out[idx] = (__bf16)v;
}

// straight fp32 -> bf16, vectorized x4
__global__ void cvt_bf16_vec(const float4* __restrict__ in, bf16x4* __restrict__ out, int n4)
{
    int i = blockIdx.x * blockDim.x + threadIdx.x;
    if (i >= n4) return;
    float4 v = in[i];
    bf16x4 o;
    o.x = (__bf16)v.x; o.y = (__bf16)v.y; o.z = (__bf16)v.z; o.w = (__bf16)v.w;
    out[i] = o;
}

extern "C" void kernel_launch(void* const* d_in, const int* in_sizes, int n_in,
                              void* d_out, int out_size, void* d_ws, size_t ws_size,
                              hipStream_t stream)
{
    const float* x  = (const float*)d_in[0];
    const float* V1 = (const float*)d_in[1];
    const float* V2 = (const float*)d_in[2];
    float* out = (float*)d_out;

    char* ws = (char*)d_ws;
    const size_t vbElems  = (size_t)SIZE_N * SIZE_N;   // 33,570,436
    const size_t padElems = (size_t)PN * PK;           // 17,334,272

    size_t off = 0;
    __bf16* Vb = (__bf16*)(ws + off);
    off += ((vbElems * 2 + 255) / 256) * 256;          // 67,141,120
    __bf16* V1b = (__bf16*)(ws + off);                 // live only through GEMM1
    __bf16* V2b = V1b + padElems;
    __bf16* hb  = (__bf16*)(ws + off);                 // overlaps V1b/V2b (live after GEMM1)
    off += ((2 * padElems * 2 + 255) / 256) * 256;     // 69,337,088
    __bf16* xb = (__bf16*)(ws + off);
    off += (size_t)BATCH * D_IN * 2;
    if (ws_size < off) return;  // workspace too small -> fail validation cleanly

    // fp32 -> bf16 conversions (V1/V2 zero-padded to PN x PK)
    {
        int total  = (int)padElems;
        int blocks = (total + 255) / 256;
        pad_cvt_bf16<<<blocks, 256, 0, stream>>>(V1, V1b, SIZE_N, SIZE_M, PK, total);
        pad_cvt_bf16<<<blocks, 256, 0, stream>>>(V2, V2b, SIZE_N, SIZE_M, PK, total);
        int n4 = BATCH * D_IN / 4;
        cvt_bf16_vec<<<(n4 + 255) / 256, 256, 0, stream>>>((const float4*)x, (bf16x4*)xb, n4);
    }

    // GEMM1: V = V1 * V2^T (padded 5888x5888x2944, store valid 5794x5794 bf16 flat)
    // 128x128 tile, 4 waves, 48KB LDS -> 3 blocks/CU; grid 2116 / cap 768 -> +9% tail
    gemm_p<0, 128, 128, 2, 2, 256, 3><<<dim3(PN / 128, PN / 128), 256, 0, stream>>>(
        V1b, PK, V2b, PK, (void*)Vb, SIZE_N, (const __bf16*)nullptr, PK, SIZE_N, SIZE_N);

    // GEMM2: h = relu(x * W1^T + b1)  (4096 x 8192 x 2048)
    // 128x256 tile, 8 waves, 72KB LDS -> 2 blocks/CU; grid 1024 = exactly 2x512 cap
    gemm_p<1, 128, 256, 2, 4, 512, 4><<<dim3(BATCH / 128, D_FF / 256), 512, 0, stream>>>(
        xb, D_IN, Vb, D_IN, (void*)hb, D_FF, Vb + OFF_B1, D_IN, BATCH, D_FF);

    // GEMM3: out = h * W2^T + b2  (4096 x 2048 x 8192)
    // 128x128 tile, 4 waves; grid 512 < cap 768 -> fully resident, zero tail
    gemm_p<2, 128, 128, 2, 2, 256, 3><<<dim3(BATCH / 128, D_OUT / 128), 256, 0, stream>>>(
        hb, D_FF, Vb + OFF_W2, D_FF, (void*)out, D_OUT, Vb + OFF_B2, D_FF, BATCH, D_OUT);
}

// Round 4
// 746.841 us; speedup vs baseline: 1.0888x; 1.0888x over previous
//
#include <hip/hip_runtime.h>
#include <hip/hip_bf16.h>

typedef __attribute__((ext_vector_type(8))) __bf16 bf16x8;
typedef __attribute__((ext_vector_type(4))) __bf16 bf16x4;
typedef __attribute__((ext_vector_type(4))) float  f32x4;

#define D_IN   2048
#define D_FF   8192
#define D_OUT  2048
#define BATCH  4096
#define SIZE_N 5794
#define SIZE_M 2897
// padded GEMM1 dims
#define PN 5888   // 23*256
#define PK 2944   // 46*64

#define OFF_B1 16777216
#define OFF_W2 16785408
#define OFF_B2 33562624

#define BK 64

__device__ __forceinline__ void gload_lds16(const __bf16* g, __bf16* l) {
    __builtin_amdgcn_global_load_lds(
        (const __attribute__((address_space(1))) void*)g,
        (__attribute__((address_space(3))) void*)l, 16, 0, 0);
}

template<int N> __device__ __forceinline__ void wait_vmcnt() {
    static_assert(N==0 || N==2 || N==5 || N==6 || N==8, "unsupported vmcnt");
    if constexpr (N == 0)      asm volatile("s_waitcnt vmcnt(0)" ::: "memory");
    else if constexpr (N == 2) asm volatile("s_waitcnt vmcnt(2)" ::: "memory");
    else if constexpr (N == 5) asm volatile("s_waitcnt vmcnt(5)" ::: "memory");
    else if constexpr (N == 6) asm volatile("s_waitcnt vmcnt(6)" ::: "memory");
    else                       asm volatile("s_waitcnt vmcnt(8)" ::: "memory");
}

// fragment reads: 16x16x32 MFMA. Lane = fl + 16*kg holds row fl, k = kg*8+[0,8)
// per ks half. LDS unit row = 64 bf16 = 8 chunks of 16B; chunk c of local row i
// stored at slot c ^ (i&7) -> a frag read's 16 fl-lanes hit 8 bank-quads x 2
// lanes = 2-way aliasing = free (m136). 32-row frags (32x32x16 shape) would be
// 4-way - the measured 4-conflicts-per-ds_read of rounds 0-2.
template<int NR>
__device__ __forceinline__ void rdFrag(const __bf16* u, int row0, int kg, int sfl, bf16x8* F) {
    #pragma unroll
    for (int r = 0; r < NR; ++r)
        #pragma unroll
        for (int ks = 0; ks < 2; ++ks)
            F[r * 2 + ks] = *(const bf16x8*)&u[(row0 + r * 16) * 64 + (((ks * 4 + kg) ^ sfl) * 8)];
}

template<int MQ, int NQ, int MH, int NH>
__device__ __forceinline__ void mmq(const bf16x8* aF, const bf16x8* bF, f32x4 (*acc)[2 * NQ]) {
    __builtin_amdgcn_s_setprio(1);
    #pragma unroll
    for (int ks = 0; ks < 2; ++ks)
        #pragma unroll
        for (int mq = 0; mq < MQ; ++mq)
            #pragma unroll
            for (int nq = 0; nq < NQ; ++nq)
                acc[MH * MQ + mq][NH * NQ + nq] = __builtin_amdgcn_mfma_f32_16x16x32_bf16(
                    aF[mq * 2 + ks], bF[nq * 2 + ks], acc[MH * MQ + mq][NH * NQ + nq], 0, 0, 0);
    __builtin_amdgcn_s_setprio(0);
}

#define PH_MID() { __builtin_amdgcn_sched_barrier(0); __builtin_amdgcn_s_barrier(); \
    asm volatile("s_waitcnt lgkmcnt(0)" ::: "memory"); __builtin_amdgcn_sched_barrier(0); }
#define PH_END() { __builtin_amdgcn_sched_barrier(0); __builtin_amdgcn_s_barrier(); }

// C = A (M x K, row-major) * B^T (B is N x K, row-major), bf16 in, fp32 acc.
// BM x BN tile, BK=64, 8 waves (2M x 4N), wave C = (BM/2) x (BN/4).
// 4 thick phases per K-tile, quadrant order (0,0),(1,0),(1,1),(0,1):
//   phase = {stage 1 unit of a future tile; ds_read quadrant frags; s_barrier;
//            lgkmcnt(0); MQ*NQ*2 MFMA (setprio-wrapped); [counted vmcnt]; s_barrier}
// Band-major units so phase p reads exactly uA(mh(p)), uB(nh(p)):
//   uA(h): for each wm: A rows wm*(BM/2) + h*RH + [0,RH)    (RH = BM/4)
//   uB(g): for each wn: B rows wn*(BN/4) + g*CH + [0,CH)    (CH = BN/8)
// Stage slots (4-6 phases ahead of first read, > HBM latency):
//   p0: uA0(t+1)->buf[t+1&1]   p1: uB1(t+1)->buf[t+1&1]
//   p2: uB0(t+2)->buf[t&1]     p3: uA1(t+2)->buf[t&1]
// Each overwrite lands >= 1 barrier after that region's last ds_read drained
// (its reader's lgkmcnt(0) precedes the phase-end barrier preceding the stage).
// Counted vmcnt (per-wave instruction counts; stage unit = GA or GB instrs):
//   p1-end: newest-allowed = {p1,p0,prev p3,prev p2} = 2(GA+GB) -> uB1(t) done
//   p3-end: newest-allowed = {p3,p2,p1} = GA+2GB -> uA0/uB0/uA1(t+1) done
//   tails: p3-end GB (t+2==nt), p1-end 0 (t+1==nt). One drain in whole kernel.
// MODE 0: bf16 store, bounds-checked, no bias (GEMM1)
// MODE 1: +bias, relu, bf16 store (GEMM2)
// MODE 2: +bias, fp32 store (GEMM3)
template<int MODE, int BM, int BN, bool SWZ>
__global__ __launch_bounds__(512, 2)
void gemm8p(const __bf16* __restrict__ A, int lda,
            const __bf16* __restrict__ B, int ldb,
            void* __restrict__ Cv, int ldc,
            const __bf16* __restrict__ bias,
            int K, int Mvalid, int Nvalid)
{
    constexpr int RH = BM / 4,  CH = BN / 8;
    constexpr int MQ = RH / 16, NQ = CH / 16;
    constexpr int GA = BM / 128, GB = BN / 128;   // gload instrs per unit per thread
    constexpr int UA = BM * 32, UB = BN * 32;     // elems per unit
    constexpr int BUFE = 2 * UA + 2 * UB;
    constexpr int W_P1 = 2 * (GA + GB);
    constexpr int W_P3 = GA + 2 * GB;

    __shared__ __bf16 lds[2 * BUFE];   // 128 KB (256x256) / 96 KB (128x256)

    const int tid  = threadIdx.x;
    const int wave = tid >> 6;
    const int lane = tid & 63;
    const int wm   = wave >> 2;   // 0..1
    const int wn   = wave & 3;    // 0..3

    int bx = blockIdx.x, by = blockIdx.y;
    if constexpr (SWZ) {   // bijective XCD swizzle (m204)
        const int nwg = gridDim.x * gridDim.y;
        const int bid = by * gridDim.x + bx;
        const int q = nwg >> 3, r = nwg & 7;
        const int xcd = bid & 7, lid = bid >> 3;
        const int nid = (xcd < r ? xcd * (q + 1) : r * (q + 1) + (xcd - r) * q) + lid;
        bx = nid % gridDim.x;
        by = nid / gridDim.x;
    }
    const int bm0 = bx * BM;
    const int bn0 = by * BN;

    // ---- staging: per gload iteration 512 threads move 8 KB = 64 rows.
    // LDS dest linear (HW: wave-uniform base + lane*16); swizzle applied by
    // pre-swizzling the per-lane GLOBAL chunk: slot tid&7 of local row srl
    // fetches chunk (tid&7) ^ (srl&7)  ->  slot sl holds chunk sl ^ (row&7).
    const int srl = tid >> 3;                       // 0..63
    const int sch = ((tid & 7) ^ (srl & 7)) * 8;    // swizzled chunk (elems)
    const __bf16* Ab = A + sch;
    const __bf16* Bb = B + sch;

    auto stA = [&](int h, int pb, int t) {
        #pragma unroll
        for (int q = 0; q < GA; ++q) {
            const int i = q * 64 + srl;                       // local unit row
            const int grow = bm0 + (i / RH) * (2 * RH) + h * RH + (i % RH);
            gload_lds16(Ab + (size_t)grow * lda + (size_t)t * BK,
                        &lds[pb * BUFE + h * UA + q * 4096 + wave * 512]);
        }
    };
    auto stB = [&](int g, int pb, int t) {
        #pragma unroll
        for (int q = 0; q < GB; ++q) {
            const int i = q * 64 + srl;
            const int grow = bn0 + (i / CH) * (2 * CH) + g * CH + (i % CH);
            gload_lds16(Bb + (size_t)grow * ldb + (size_t)t * BK,
                        &lds[pb * BUFE + 2 * UA + g * UB + q * 4096 + wave * 512]);
        }
    };

    // fragment coords
    const int fl   = lane & 15;
    const int kg   = lane >> 4;       // 0..3
    const int sfl  = fl & 7;
    const int aRow = wm * RH + fl;
    const int bRow = wn * CH + fl;

    bf16x8 aF[2 * MQ], bF[2 * NQ];
    f32x4  acc[2 * MQ][2 * NQ] = {};

    const int nt = K / BK;   // >= 32 for all callers

    // prologue (issue order matters for the counted waits):
    stB(0, 0, 0); stA(1, 0, 0); stA(0, 0, 0); stB(1, 0, 0);
    stB(0, 1, 1); stA(1, 1, 1);
    wait_vmcnt<W_P3>();               // uB0/uA1/uA0 of tile 0 landed
    __builtin_amdgcn_s_barrier();

    for (int t = 0; t < nt; ++t) {
        const int pc = t & 1, pn = pc ^ 1;
        const __bf16* bufc = &lds[pc * BUFE];

        // ---- phase 0: quadrant (0,0)
        if (t + 1 < nt) stA(0, pn, t + 1);
        rdFrag<MQ>(bufc + 0 * UA,      aRow, kg, sfl, aF);
        rdFrag<NQ>(bufc + 2 * UA,      bRow, kg, sfl, bF);
        PH_MID();
        mmq<MQ, NQ, 0, 0>(aF, bF, acc);
        PH_END();

        // ---- phase 1: quadrant (1,0)   (B0 cached)
        if (t + 1 < nt) stB(1, pn, t + 1);
        rdFrag<MQ>(bufc + 1 * UA,      aRow, kg, sfl, aF);
        PH_MID();
        mmq<MQ, NQ, 1, 0>(aF, bF, acc);
        if (t + 1 < nt) wait_vmcnt<W_P1>(); else wait_vmcnt<0>();
        PH_END();

        // ---- phase 2: quadrant (1,1)   (A1 cached)
        if (t + 2 < nt) stB(0, pc, t + 2);
        rdFrag<NQ>(bufc + 2 * UA + UB, bRow, kg, sfl, bF);
        PH_MID();
        mmq<MQ, NQ, 1, 1>(aF, bF, acc);
        PH_END();

        // ---- phase 3: quadrant (0,1)   (B1 cached, A0 re-read)
        if (t + 2 < nt) stA(1, pc, t + 2);
        rdFrag<MQ>(bufc + 0 * UA,      aRow, kg, sfl, aF);
        PH_MID();
        mmq<MQ, NQ, 0, 1>(aF, bF, acc);
        if (t + 1 < nt) { if (t + 2 < nt) wait_vmcnt<W_P3>(); else wait_vmcnt<2>(); }
        PH_END();
    }

    // epilogue: 16x16x32 C/D layout: col = lane&15, row = (lane>>4)*4 + reg (m89)
    const int er = kg * 4;
    #pragma unroll
    for (int mh = 0; mh < 2; ++mh)
    #pragma unroll
    for (int mq = 0; mq < MQ; ++mq)
        #pragma unroll
        for (int nh = 0; nh < 2; ++nh)
        #pragma unroll
        for (int nq = 0; nq < NQ; ++nq) {
            const int col = bn0 + wn * (2 * CH) + nh * CH + nq * 16 + fl;
            #pragma unroll
            for (int reg = 0; reg < 4; ++reg) {
                const int row = bm0 + wm * (2 * RH) + mh * RH + mq * 16 + er + reg;
                float v = acc[mh * MQ + mq][nh * NQ + nq][reg];
                if constexpr (MODE == 0) {
                    if (row < Mvalid && col < Nvalid)
                        ((__bf16*)Cv)[(size_t)row * ldc + col] = (__bf16)v;
                } else if constexpr (MODE == 1) {
                    v += (float)bias[col];
                    v = v > 0.f ? v : 0.f;
                    ((__bf16*)Cv)[(size_t)row * ldc + col] = (__bf16)v;
                } else {
                    v += (float)bias[col];
                    ((float*)Cv)[(size_t)row * ldc + col] = v;
                }
            }
        }
}

// fp32 (rows x cols) -> zero-padded bf16 (prows x pcols), row-major
__global__ void pad_cvt_bf16(const float* __restrict__ in, __bf16* __restrict__ out,
                             int rows, int cols, int pcols, int total)
{
    int idx = blockIdx.x * blockDim.x + threadIdx.x;
    if (idx >= total) return;
    int r = idx / pcols;
    int c = idx - r * pcols;
    float v = (r < rows && c < cols) ? in[(size_t)r * cols + c] : 0.0f;
    out[idx] = (__bf16)v;
}

// straight fp32 -> bf16, vectorized x4
__global__ void cvt_bf16_vec(const float4* __restrict__ in, bf16x4* __restrict__ out, int n4)
{
    int i = blockIdx.x * blockDim.x + threadIdx.x;
    if (i >= n4) return;
    float4 v = in[i];
    bf16x4 o;
    o.x = (__bf16)v.x; o.y = (__bf16)v.y; o.z = (__bf16)v.z; o.w = (__bf16)v.w;
    out[i] = o;
}

extern "C" void kernel_launch(void* const* d_in, const int* in_sizes, int n_in,
                              void* d_out, int out_size, void* d_ws, size_t ws_size,
                              hipStream_t stream)
{
    const float* x  = (const float*)d_in[0];
    const float* V1 = (const float*)d_in[1];
    const float* V2 = (const float*)d_in[2];
    float* out = (float*)d_out;

    char* ws = (char*)d_ws;
    const size_t vbElems  = (size_t)SIZE_N * SIZE_N;   // 33,570,436
    const size_t padElems = (size_t)PN * PK;           // 17,334,272

    size_t off = 0;
    __bf16* Vb = (__bf16*)(ws + off);
    off += ((vbElems * 2 + 255) / 256) * 256;          // 67,141,120
    __bf16* V1b = (__bf16*)(ws + off);                 // live only through GEMM1
    __bf16* V2b = V1b + padElems;
    __bf16* hb  = (__bf16*)(ws + off);                 // overlaps V1b/V2b (live after GEMM1)
    off += ((2 * padElems * 2 + 255) / 256) * 256;     // 69,337,088
    __bf16* xb = (__bf16*)(ws + off);
    off += (size_t)BATCH * D_IN * 2;
    if (ws_size < off) return;  // workspace too small -> fail validation cleanly

    // fp32 -> bf16 conversions (V1/V2 zero-padded to PN x PK)
    {
        int total  = (int)padElems;
        int blocks = (total + 255) / 256;
        pad_cvt_bf16<<<blocks, 256, 0, stream>>>(V1, V1b, SIZE_N, SIZE_M, PK, total);
        pad_cvt_bf16<<<blocks, 256, 0, stream>>>(V2, V2b, SIZE_N, SIZE_M, PK, total);
        int n4 = BATCH * D_IN / 4;
        cvt_bf16_vec<<<(n4 + 255) / 256, 256, 0, stream>>>((const float4*)x, (bf16x4*)xb, n4);
    }

    // GEMM1: V = V1 * V2^T (padded 5888x5888x2944, valid 5794x5794 bf16 flat)
    gemm8p<0, 256, 256, true><<<dim3(PN / 256, PN / 256), 512, 0, stream>>>(
        V1b, PK, V2b, PK, (void*)Vb, SIZE_N, (const __bf16*)nullptr, PK, SIZE_N, SIZE_N);

    // GEMM2: h = relu(x * W1^T + b1)  (4096 x 8192 x 2048); grid 512 = 2 full rounds
    gemm8p<1, 256, 256, false><<<dim3(BATCH / 256, D_FF / 256), 512, 0, stream>>>(
        xb, D_IN, Vb, D_IN, (void*)hb, D_FF, Vb + OFF_B1, D_IN, BATCH, D_FF);

    // GEMM3: out = h * W2^T + b2  (4096 x 2048 x 8192)
    // 128x256 tile -> grid 32x8 = 256 blocks = exactly one full round at 1 block/CU
    gemm8p<2, 128, 256, false><<<dim3(BATCH / 128, D_OUT / 256), 512, 0, stream>>>(
        hb, D_FF, Vb + OFF_W2, D_FF, (void*)out, D_OUT, Vb + OFF_B2, D_FF, BATCH, D_OUT);
}